// Round 2
// baseline (105.858 us; speedup 1.0000x reference)
//
#include <hip/hip_runtime.h>
#include <hip/hip_bf16.h>

// SupConLoss, B=8192, D=128, T=0.1. Output: single fp32 scalar.
//
// Dtype-robust pipeline:
//   1) supcon_detect  — classifies feature buffer (fp32 vs bf16) and label
//      buffer (int64 vs int32) from bit patterns; writes 2 flags to ws.
//   2) supcon_convert — canonicalizes features -> bf16 copy in ws (RTNE),
//      labels -> int32 copy in ws.
//   3) supcon_main    — fused bf16-MFMA GEMM (F·F^T)/T + masked exp/pos
//      accumulation, per-(chunk,row) partials to ws.
//   4) supcon_reduce / supcon_final — row partials -> scalar loss.
//
// Math: with ANY fixed shift M (instead of per-row max), per row i:
//   mean_log_prob_i = p_i/n_i - M - log(sum_{j!=i} exp(s_ij - M))
// identical to the reference (shift cancels). M=10.5 >= max s_ij for
// unit-norm features (s <= 10.2 incl. bf16 rounding): no overflow, and
// min exp argument is ~-21 -> no underflow-to-zero of the full sum.

#define BB 8192
#define DD 128
#define NC 8                 // column chunks (grid.x)
#define COLCHUNK (BB / NC)   // 1024 cols per WG
#define ITERS (COLCHUNK / 128)
#define TEMP_INV 10.0f
#define MSHIFT 10.5f

typedef __bf16 bf16x8 __attribute__((ext_vector_type(8)));
typedef float floatx4 __attribute__((ext_vector_type(4)));

__device__ inline unsigned short f2bf(float f) {           // RTNE fp32->bf16
    unsigned u = __float_as_uint(f);
    return (unsigned short)((u + 0x7FFFu + ((u >> 16) & 1u)) >> 16);
}

// ---- 1) dtype detector (1 wave) ----
__global__ void supcon_detect(const unsigned short* __restrict__ feats_raw,
                              const int* __restrict__ labels_raw,
                              int* __restrict__ flags)
{
    int lane = threadIdx.x;  // 64 threads
    // If features are fp32 (little-endian), EVEN bf16-slots are low mantissa
    // halves -> garbage exponents. For true bf16 unit rows, sum of squares of
    // the 64 even slots of row 0 is ~0.5.
    unsigned ue = ((unsigned)feats_raw[2 * lane]) << 16;
    float fe = __uint_as_float(ue);
    float ve = fe * fe;
    // If labels are int64 (values < 100), all high int32 words are 0.
    int odd_or = labels_raw[2 * lane + 1];
#pragma unroll
    for (int m = 1; m < 64; m <<= 1) {
        ve += __shfl_xor(ve, m, 64);
        odd_or |= __shfl_xor(odd_or, m, 64);
    }
    if (lane == 0) {
        bool feats_bf16 = (ve > 0.05f) && (ve < 4.0f);   // NaN-safe: NaN -> false
        flags[0] = feats_bf16 ? 0 : 1;                   // 1 = features are fp32
        flags[1] = (odd_or == 0) ? 1 : 0;                // 1 = labels are int64
    }
}

// ---- 2) canonicalize: features -> bf16 ws copy, labels -> int32 ws copy ----
__global__ __launch_bounds__(256) void supcon_convert(
    const void* __restrict__ fin, const void* __restrict__ lin,
    const int* __restrict__ flags,
    unsigned short* __restrict__ fbf, int* __restrict__ lab)
{
    int gid = blockIdx.x * 256 + threadIdx.x;    // 262144 threads x 4 elements
    if (flags[0]) {
        float4 v = ((const float4*)fin)[gid];
        ushort4 o;
        o.x = f2bf(v.x); o.y = f2bf(v.y); o.z = f2bf(v.z); o.w = f2bf(v.w);
        ((ushort4*)fbf)[gid] = o;
    } else {
        ((ushort4*)fbf)[gid] = ((const ushort4*)fin)[gid];
    }
    if (blockIdx.x < 32) {
        int li = blockIdx.x * 256 + threadIdx.x;
        const int* L = (const int*)lin;
        lab[li] = flags[1] ? L[2 * li] : L[li];
    }
}

// ---- 3) fused GEMM + masked softmax partials ----
__global__ __launch_bounds__(256, 2) void supcon_main(
    const unsigned short* __restrict__ Fb, const int* __restrict__ labels,
    float* __restrict__ e_part, float* __restrict__ p_part,
    float* __restrict__ n_part)
{
    __shared__ unsigned char ldsbuf[32768];       // 128 rows x 256B bf16, XOR-swizzled
    __shared__ float red[3][128][2];

    const int tid  = threadIdx.x;
    const int lane = tid & 63;
    const int wid  = tid >> 6;
    const int wrow = wid >> 1;
    const int wcol = wid & 1;
    const int quad = lane >> 4;
    const int l16  = lane & 15;

    const int chunk   = blockIdx.x;
    const int rowbase = blockIdx.y * 128;
    const int colchunkbase = chunk * COLCHUNK;

    // stage A tile (rows rowbase..+127, full K=128 -> 256B/row)
    {
        const unsigned char* gA = (const unsigned char*)(Fb) + (size_t)rowbase * 256;
#pragma unroll
        for (int rnd = 0; rnd < 8; ++rnd) {
            int off = rnd * 4096 + tid * 16;
            int row = off >> 8;
            int g   = (off >> 4) & 15;
            int gs  = g ^ (row & 15);              // XOR swizzle: <=2-way conflict (free)
            int4 v  = *(const int4*)(gA + off);
            *(int4*)(&ldsbuf[row * 256 + gs * 16]) = v;
        }
    }
    __syncthreads();

    // A fragments (A[m=l16][k=quad*8+j], 4 row-subtiles x 4 k-steps), kept in VGPRs
    bf16x8 afrag[4][4];
#pragma unroll
    for (int ti = 0; ti < 4; ++ti) {
        int row = wrow * 64 + ti * 16 + l16;
#pragma unroll
        for (int k = 0; k < 4; ++k) {
            int g  = k * 4 + quad;
            int gs = g ^ (row & 15);
            afrag[ti][k] = *(const bf16x8*)(&ldsbuf[row * 256 + gs * 16]);
        }
    }

    int lab_row[16];
#pragma unroll
    for (int ti = 0; ti < 4; ++ti)
#pragma unroll
        for (int r = 0; r < 4; ++r)
            lab_row[ti * 4 + r] = labels[rowbase + wrow * 64 + ti * 16 + quad * 4 + r];

    float e_acc[16], p_acc[16], n_acc[16];
#pragma unroll
    for (int i = 0; i < 16; ++i) { e_acc[i] = 0.0f; p_acc[i] = 0.0f; n_acc[i] = 0.0f; }

    __syncthreads();   // A-frags extracted; ldsbuf reusable for B tiles

    for (int it = 0; it < ITERS; ++it) {
        int colbase = colchunkbase + it * 128;
        const unsigned char* gB = (const unsigned char*)(Fb) + (size_t)colbase * 256;
#pragma unroll
        for (int rnd = 0; rnd < 8; ++rnd) {
            int off = rnd * 4096 + tid * 16;
            int row = off >> 8;
            int g   = (off >> 4) & 15;
            int gs  = g ^ (row & 15);
            int4 v  = *(const int4*)(gB + off);
            *(int4*)(&ldsbuf[row * 256 + gs * 16]) = v;
        }
        __syncthreads();

#pragma unroll
        for (int tj = 0; tj < 4; ++tj) {
            int coll = wcol * 64 + tj * 16 + l16;   // B[n=l16][k=quad*8+j]
            bf16x8 bfrag[4];
#pragma unroll
            for (int k = 0; k < 4; ++k) {
                int g  = k * 4 + quad;
                int gs = g ^ (coll & 15);
                bfrag[k] = *(const bf16x8*)(&ldsbuf[coll * 256 + gs * 16]);
            }
            floatx4 acc[4];
#pragma unroll
            for (int ti = 0; ti < 4; ++ti) acc[ti] = (floatx4){0.f, 0.f, 0.f, 0.f};
#pragma unroll
            for (int k = 0; k < 4; ++k)
#pragma unroll
                for (int ti = 0; ti < 4; ++ti)
                    acc[ti] = __builtin_amdgcn_mfma_f32_16x16x32_bf16(
                        afrag[ti][k], bfrag[k], acc[ti], 0, 0, 0);

            int col   = colbase + coll;
            int lab_c = labels[col];
#pragma unroll
            for (int ti = 0; ti < 4; ++ti) {
                int row0 = rowbase + wrow * 64 + ti * 16 + quad * 4;
#pragma unroll
                for (int r = 0; r < 4; ++r) {
                    // C/D: D[row=quad*4+r][col=l16] (m89/m91 verified)
                    float s = acc[ti][r] * TEMP_INV;
                    int row = row0 + r;
                    bool nd  = (row != col);
                    float ex = __expf(s - MSHIFT);
                    bool pos = nd && (lab_c == lab_row[ti * 4 + r]);
                    e_acc[ti * 4 + r] += nd ? ex : 0.0f;
                    p_acc[ti * 4 + r] += pos ? s : 0.0f;
                    n_acc[ti * 4 + r] += pos ? 1.0f : 0.0f;
                }
            }
        }
        __syncthreads();
    }

    // reduce across 16 column-lanes (xor over lane bits 0..3)
#pragma unroll
    for (int i = 0; i < 16; ++i) {
        float e = e_acc[i], p = p_acc[i], n = n_acc[i];
#pragma unroll
        for (int m = 1; m < 16; m <<= 1) {
            e += __shfl_xor(e, m, 64);
            p += __shfl_xor(p, m, 64);
            n += __shfl_xor(n, m, 64);
        }
        if (l16 == 0) {
            int row_local = wrow * 64 + (i >> 2) * 16 + quad * 4 + (i & 3);
            red[0][row_local][wcol] = e;
            red[1][row_local][wcol] = p;
            red[2][row_local][wcol] = n;
        }
    }
    __syncthreads();

    if (tid < 128) {
        size_t idx = (size_t)chunk * BB + (rowbase + tid);
        e_part[idx] = red[0][tid][0] + red[0][tid][1];
        p_part[idx] = red[1][tid][0] + red[1][tid][1];
        n_part[idx] = red[2][tid][0] + red[2][tid][1];
    }
}

// ---- 4) row partials -> 32 block partials ----
__global__ __launch_bounds__(256) void supcon_reduce(
    const float* __restrict__ e_part, const float* __restrict__ p_part,
    const float* __restrict__ n_part, float* __restrict__ partials)
{
    int row = blockIdx.x * 256 + threadIdx.x;
    float e = 0.f, p = 0.f, n = 0.f;
#pragma unroll
    for (int c = 0; c < NC; ++c) {
        size_t idx = (size_t)c * BB + row;
        e += e_part[idx]; p += p_part[idx]; n += n_part[idx];
    }
    float contrib = 0.f, vld = 0.f;
    if (n > 0.5f) {
        vld = 1.0f;
        contrib = -(p / n - MSHIFT - logf(e));
    }
#pragma unroll
    for (int m = 1; m < 64; m <<= 1) {
        contrib += __shfl_xor(contrib, m, 64);
        vld     += __shfl_xor(vld, m, 64);
    }
    __shared__ float rl[4], rv[4];
    int lane = threadIdx.x & 63, w = threadIdx.x >> 6;
    if (lane == 0) { rl[w] = contrib; rv[w] = vld; }
    __syncthreads();
    if (threadIdx.x == 0) {
        partials[blockIdx.x * 2]     = rl[0] + rl[1] + rl[2] + rl[3];
        partials[blockIdx.x * 2 + 1] = rv[0] + rv[1] + rv[2] + rv[3];
    }
}

__global__ void supcon_final(const float* __restrict__ partials, float* __restrict__ out)
{
    int lane = threadIdx.x;   // 64 threads
    float L = (lane < 32) ? partials[lane * 2]     : 0.0f;
    float V = (lane < 32) ? partials[lane * 2 + 1] : 0.0f;
#pragma unroll
    for (int m = 1; m < 64; m <<= 1) {
        L += __shfl_xor(L, m, 64);
        V += __shfl_xor(V, m, 64);
    }
    if (lane == 0) out[0] = (V > 0.5f) ? (L / V) : 0.0f;
}

extern "C" void kernel_launch(void* const* d_in, const int* in_sizes, int n_in,
                              void* d_out, int out_size, void* d_ws, size_t ws_size,
                              hipStream_t stream)
{
    const void* Fin = d_in[0];
    const void* Lin = d_in[1];

    // ws layout
    unsigned short* fbf = (unsigned short*)d_ws;                          // 2 MB bf16 copy
    int*   lab      = (int*)((char*)d_ws + (size_t)BB * DD * 2);          // 32 KB
    float* e_part   = (float*)((char*)lab + (size_t)BB * 4);              // NC*B floats
    float* p_part   = e_part + (size_t)NC * BB;
    float* n_part   = p_part + (size_t)NC * BB;
    float* partials = n_part + (size_t)NC * BB;                           // 64 floats
    int*   flags    = (int*)(partials + 64);                              // 2 ints

    supcon_detect<<<1, 64, 0, stream>>>((const unsigned short*)Fin, (const int*)Lin, flags);
    supcon_convert<<<(BB * DD / 4 + 255) / 256, 256, 0, stream>>>(Fin, Lin, flags, fbf, lab);

    dim3 grid(NC, BB / 128);
    supcon_main<<<grid, 256, 0, stream>>>(fbf, lab, e_part, p_part, n_part);
    supcon_reduce<<<32, 256, 0, stream>>>(e_part, p_part, n_part, partials);
    supcon_final<<<1, 64, 0, stream>>>(partials, (float*)d_out);
}